// Round 11
// baseline (247.869 us; speedup 1.0000x reference)
//
#include <hip/hip_runtime.h>
#include <math.h>

#define BATCH 131072
#define DIM 256
#define NK 5
#define BT 3.0f
#define NBLK 1024    // 4 blocks/CU x 256 CU, exactly co-resident
#define NTHR 512     // 8 waves/block -> 32 waves/CU
#define ITERS 4      // BATCH / (NBLK * 8 waves * 4 rows)

typedef float fvec4 __attribute__((ext_vector_type(4)));   // clang vector for nt-store (r5 lesson)

__global__ __launch_bounds__(NTHR, 8) void rqs_kernel(
    const float* __restrict__ u,
    const float* __restrict__ wp,
    const float* __restrict__ hp,
    const float* __restrict__ dp,
    float* __restrict__ x_out,
    float* __restrict__ ld_out)
{
    // r9/r10 post-mortem: latency-overlap attempts (u-prefetch +2%, depth-2 LDS
    // pipeline 0%) are null -> TLP already covers individual latencies. Remaining
    // reducible cost is per-iteration serial overhead (8 iteration walls, 12-deep
    // dependent shfl reduce per 2 rows) and trans-op count (8 rcp + 8 log / iter).
    // This round: 4 rows/iter (ITERS=4) -> half the walls, 4 interleaved reduce
    // chains, ld written as one dwordx4; and ONE log per row via
    // sum_j log(t_j) == log(prod_j t_j)  (tail terms == 1, product in f32 range).
    //
    // Table: split per-(bin,dim) records, 16 B/lane gather stride (conflict-free
    // ds_read_b128; interleaved 32 B stride cost 6.36M conflict cycles, r0).
    //   tabA[k*DIM+dim] = (xk, 1/width, s = dk+dk1-2*delta, delta)
    //   tabB[k*DIM+dim] = (p = h*(delta-dk), q = h*dk, yk, rb = 2*(delta-dk))
    // Math:  theta = (uc-xk)*iw
    //        denom = fma(fma(-s,th,s),th,delta)
    //        num   = th*fma(p,th,q)
    //        ldq   = fma(fma(s,th,rb),th,dk)
    //        term  = ldq * dlt^2 * invd^2      (== 1 in the identity tails)
    //        ld_row = log(prod_j term_j)
    __shared__ float4 tabA[NK * DIM];   // 20480 B
    __shared__ float4 tabB[NK * DIM];   // 20480 B ; total 40960 -> 4 blocks = 160 KiB/CU
    const int tid = threadIdx.x;

    if (tid < DIM) {
        const int dm = tid;
        float v[NK], wid[NK], xpos[NK], hei[NK], ypos[NK], dv[NK + 1];
        float mx, sum, scale, c;

        mx = -1e30f;
        #pragma unroll
        for (int k = 0; k < NK; k++) { v[k] = wp[dm * NK + k]; mx = fmaxf(mx, v[k]); }
        sum = 0.f;
        #pragma unroll
        for (int k = 0; k < NK; k++) { v[k] = expf(v[k] - mx); sum += v[k]; }
        scale = 6.0f / sum;
        c = -BT;
        #pragma unroll
        for (int k = 0; k < NK; k++) { wid[k] = v[k] * scale; xpos[k] = c; c += wid[k]; }

        mx = -1e30f;
        #pragma unroll
        for (int k = 0; k < NK; k++) { v[k] = hp[dm * NK + k]; mx = fmaxf(mx, v[k]); }
        sum = 0.f;
        #pragma unroll
        for (int k = 0; k < NK; k++) { v[k] = expf(v[k] - mx); sum += v[k]; }
        scale = 6.0f / sum;
        c = -BT;
        #pragma unroll
        for (int k = 0; k < NK; k++) { hei[k] = v[k] * scale; ypos[k] = c; c += hei[k]; }

        dv[0] = 1.0f; dv[NK] = 1.0f;
        #pragma unroll
        for (int k = 0; k < 4; k++) dv[1 + k] = log1pf(expf(dp[dm * 4 + k]));

        #pragma unroll
        for (int k = 0; k < NK; k++) {
            float iw  = 1.0f / wid[k];
            float dlt = hei[k] * iw;
            float dk  = dv[k], dk1 = dv[k + 1];
            tabA[k * DIM + dm] = make_float4(xpos[k], iw, dk + dk1 - 2.0f * dlt, dlt);
            tabB[k * DIM + dm] = make_float4(hei[k] * (dlt - dk), hei[k] * dk,
                                             ypos[k], 2.0f * (dlt - dk));
        }
    }
    __syncthreads();

    const int lane = tid & 63;
    const int wv   = tid >> 6;

    // thread owns dims lane, lane+64, lane+128, lane+192; preload interior x-knots
    float kn[4][4];
    #pragma unroll
    for (int j = 0; j < 4; j++)
        #pragma unroll
        for (int i = 0; i < 4; i++)
            kn[j][i] = tabA[(i + 1) * DIM + lane + 64 * j].x;

    const int g = (blockIdx.x << 3) | wv;   // global wave id, 0..8191

    for (int it = 0; it < ITERS; it++) {
        const int r0 = (it << 15) | (g << 2);   // 4 contiguous rows per wave per iter
        const float* up = u + (size_t)r0 * DIM + lane;

        float uin[4][4];
        #pragma unroll
        for (int rr = 0; rr < 4; rr++)
            #pragma unroll
            for (int j = 0; j < 4; j++)
                uin[rr][j] = up[rr * DIM + 64 * j];

        float acc[4];
        #pragma unroll
        for (int rr = 0; rr < 4; rr++) {
            float xo[4];
            float prod = 1.0f;
            #pragma unroll
            for (int j = 0; j < 4; j++) {
                float uval = uin[rr][j];
                float uc = fminf(fmaxf(uval, -BT), BT);
                int idx = 0;
                idx += (uc >= kn[j][0]);
                idx += (uc >= kn[j][1]);
                idx += (uc >= kn[j][2]);
                idx += (uc >= kn[j][3]);
                const int off = idx * DIM + lane + 64 * j;
                float4 A  = tabA[off];
                float4 Bv = tabB[off];
                float xk = A.x, iw = A.y, s = A.z, dlt = A.w;
                float p = Bv.x, q = Bv.y, yk = Bv.z, rb = Bv.w;

                float th    = (uc - xk) * iw;
                float dk    = fmaf(-0.5f, rb, dlt);
                float r2    = dlt * dlt;
                float denom = fmaf(fmaf(-s, th, s), th, dlt);
                float invd  = __builtin_amdgcn_rcpf(denom);
                float num   = th * fmaf(p, th, q);
                float x_in  = fmaf(num, invd, yk);
                float ldq   = fmaf(fmaf(s, th, rb), th, dk);
                float term  = ldq * r2 * invd * invd;   // == 1 (to fp eps) in tails

                xo[j] = (uc == uval) ? x_in : uval;
                prod *= term;
            }
            acc[rr] = __logf(prod);    // ONE log per row instead of four

            float* xp = x_out + (size_t)(r0 + rr) * DIM + lane;
            #pragma unroll
            for (int j = 0; j < 4; j++)
                __builtin_nontemporal_store(xo[j], xp + 64 * j);
        }

        // 4 independent reduce chains interleave through the LDS pipe
        #pragma unroll
        for (int off = 32; off > 0; off >>= 1) {
            acc[0] += __shfl_down(acc[0], off, 64);
            acc[1] += __shfl_down(acc[1], off, 64);
            acc[2] += __shfl_down(acc[2], off, 64);
            acc[3] += __shfl_down(acc[3], off, 64);
        }
        if (lane == 0) {
            fvec4 lv = { acc[0], acc[1], acc[2], acc[3] };
            __builtin_nontemporal_store(lv, (fvec4*)(ld_out + r0));   // r0 % 4 == 0, 16B aligned
        }
    }
}

extern "C" void kernel_launch(void* const* d_in, const int* in_sizes, int n_in,
                              void* d_out, int out_size, void* d_ws, size_t ws_size,
                              hipStream_t stream) {
    const float* u  = (const float*)d_in[0];
    const float* w  = (const float*)d_in[1];
    const float* h  = (const float*)d_in[2];
    const float* dd = (const float*)d_in[3];
    float* x  = (float*)d_out;
    float* ld = x + (size_t)BATCH * DIM;
    rqs_kernel<<<NBLK, NTHR, 0, stream>>>(u, w, h, dd, x, ld);
}